// Round 1
// baseline (591.862 us; speedup 1.0000x reference)
//
#include <hip/hip_runtime.h>

// ---------------------------------------------------------------------------
// 2-layer GCN + linear head on MI355X.
// Strategy: build dst-sorted CSR once (int atomics only), then per-layer:
//   t = h @ W  (dense, LDS-staged W + X rows)
//   h' = relu(dinv_i * sum_e w_e * t[src_e] + dinv_i^2 * t[i] + b)
// Aggregation: 16 lanes per node, float4 per lane (64 features), no fp32 atomics.
// ---------------------------------------------------------------------------

__global__ void zero_i32_kernel(int* __restrict__ p, int n) {
    int i = blockIdx.x * blockDim.x + threadIdx.x;
    if (i < n) p[i] = 0;
}

__global__ void hist_kernel(const int* __restrict__ dst, int E, int* __restrict__ deg) {
    int i = blockIdx.x * blockDim.x + threadIdx.x;
    int stride = gridDim.x * blockDim.x;
    for (; i < E; i += stride) atomicAdd(&deg[dst[i]], 1);
}

__global__ void dinv_kernel(const int* __restrict__ deg, float* __restrict__ dinv, int N) {
    int i = blockIdx.x * blockDim.x + threadIdx.x;
    if (i < N) dinv[i] = 1.0f / sqrtf((float)deg[i] + 1.0f);
}

// Single-block exclusive scan of deg -> offs (and cursor copy). 1024 thr, 4 elem/thr.
__global__ void scan_kernel(const int* __restrict__ deg, int* __restrict__ offs,
                            int* __restrict__ cursor, int N, int E) {
    __shared__ int sm[1024];
    const int tid = threadIdx.x;
    int carry = 0;
    const int CH = 4096;
    for (int base = 0; base < N; base += CH) {
        int v[4];
        int s = 0;
#pragma unroll
        for (int j = 0; j < 4; j++) {
            int idx = base + tid * 4 + j;
            v[j] = (idx < N) ? deg[idx] : 0;
            s += v[j];
        }
        sm[tid] = s;
        __syncthreads();
        for (int off = 1; off < 1024; off <<= 1) {
            int t = (tid >= off) ? sm[tid - off] : 0;
            __syncthreads();
            sm[tid] += t;
            __syncthreads();
        }
        int excl = sm[tid] - s;
        int run = carry + excl;
#pragma unroll
        for (int j = 0; j < 4; j++) {
            int idx = base + tid * 4 + j;
            if (idx < N) { offs[idx] = run; cursor[idx] = run; }
            run += v[j];
        }
        carry += sm[1023];
        __syncthreads();
    }
    if (tid == 0) offs[N] = E;
}

__global__ void scatter_kernel(const int* __restrict__ src, const int* __restrict__ dst,
                               int E, const float* __restrict__ dinv,
                               int* __restrict__ cursor, int* __restrict__ csr_src,
                               float* __restrict__ csr_w) {
    int i = blockIdx.x * blockDim.x + threadIdx.x;
    int stride = gridDim.x * blockDim.x;
    for (; i < E; i += stride) {
        int s = src[i];
        int d = dst[i];
        int pos = atomicAdd(&cursor[d], 1);
        csr_src[pos] = s;
        csr_w[pos] = dinv[s];
    }
}

// Y[N,OUTC] = X[N,64] @ W[64,OUTC] (+ bias). Block 256 threads.
template <int OUTC, bool BIAS>
__global__ __launch_bounds__(256) void gemm_kernel(const float* __restrict__ X,
                                                   const float* __restrict__ W,
                                                   const float* __restrict__ bias,
                                                   float* __restrict__ Y, int N) {
    constexpr int TPR = OUTC / 4;    // threads per row
    constexpr int RPB = 256 / TPR;   // rows per block
    __shared__ float Ws[64 * OUTC];
    __shared__ float Xs[RPB * 65];   // +1 pad: bank-conflict-free column reads

    const int tid = threadIdx.x;
    const int row0 = blockIdx.x * RPB;

    // stage W (row-major [64][OUTC]) via float4
    for (int l = tid; l < 64 * OUTC / 4; l += 256) {
        ((float4*)Ws)[l] = ((const float4*)W)[l];
    }
    // stage X rows (padded stride 65)
    for (int l = tid; l < RPB * 16; l += 256) {
        int r = l / 16, kq = l % 16;
        float4 xv = make_float4(0.f, 0.f, 0.f, 0.f);
        if (row0 + r < N) xv = ((const float4*)(X + (long)(row0 + r) * 64))[kq];
        Xs[r * 65 + kq * 4 + 0] = xv.x;
        Xs[r * 65 + kq * 4 + 1] = xv.y;
        Xs[r * 65 + kq * 4 + 2] = xv.z;
        Xs[r * 65 + kq * 4 + 3] = xv.w;
    }
    __syncthreads();

    const int r = tid / TPR;
    const int c4 = tid % TPR;
    float4 acc = make_float4(0.f, 0.f, 0.f, 0.f);
#pragma unroll
    for (int k = 0; k < 64; k++) {
        float x = Xs[r * 65 + k];
        float4 w = *(const float4*)&Ws[k * OUTC + c4 * 4];
        acc.x += x * w.x;
        acc.y += x * w.y;
        acc.z += x * w.z;
        acc.w += x * w.w;
    }
    const int row = row0 + r;
    if (row < N) {
        if (BIAS) {
            float4 b = *(const float4*)&bias[c4 * 4];
            acc.x += b.x; acc.y += b.y; acc.z += b.z; acc.w += b.w;
        }
        *(float4*)&Y[(long)row * OUTC + c4 * 4] = acc;
    }
}

// out[i] = relu( dinv_i * sum_e w_e * T[src_e] + dinv_i^2 * T[i] + b )
// 16 lanes per node, float4 per lane (64 features). 16 nodes per 256-thr block.
template <bool RELU>
__global__ __launch_bounds__(256) void agg_kernel(const float* __restrict__ T,
                                                  const int* __restrict__ offs,
                                                  const int* __restrict__ csr_src,
                                                  const float* __restrict__ csr_w,
                                                  const float* __restrict__ dinv,
                                                  const float* __restrict__ bias,
                                                  float* __restrict__ Y, int N) {
    const int tid = threadIdx.x;
    const int node = blockIdx.x * 16 + (tid >> 4);
    const int l16 = tid & 15;
    if (node >= N) return;

    const int start = offs[node];
    const int end = offs[node + 1];
    float4 acc = make_float4(0.f, 0.f, 0.f, 0.f);
    for (int e = start; e < end; e++) {
        const int s = csr_src[e];
        const float w = csr_w[e];
        const float4 hv = *(const float4*)&T[(long)s * 64 + l16 * 4];
        acc.x += w * hv.x;
        acc.y += w * hv.y;
        acc.z += w * hv.z;
        acc.w += w * hv.w;
    }
    const float di = dinv[node];
    const float dii = di * di;
    const float4 self = *(const float4*)&T[(long)node * 64 + l16 * 4];
    const float4 b4 = *(const float4*)&bias[l16 * 4];
    float4 o;
    o.x = di * acc.x + dii * self.x + b4.x;
    o.y = di * acc.y + dii * self.y + b4.y;
    o.z = di * acc.z + dii * self.z + b4.z;
    o.w = di * acc.w + dii * self.w + b4.w;
    if (RELU) {
        o.x = fmaxf(o.x, 0.f);
        o.y = fmaxf(o.y, 0.f);
        o.z = fmaxf(o.z, 0.f);
        o.w = fmaxf(o.w, 0.f);
    }
    *(float4*)&Y[(long)node * 64 + l16 * 4] = o;
}

extern "C" void kernel_launch(void* const* d_in, const int* in_sizes, int n_in,
                              void* d_out, int out_size, void* d_ws, size_t ws_size,
                              hipStream_t stream) {
    const float* x  = (const float*)d_in[0];
    const int*   ei = (const int*)d_in[1];
    const float* W1 = (const float*)d_in[2];
    const float* b1 = (const float*)d_in[3];
    const float* W2 = (const float*)d_in[4];
    const float* b2 = (const float*)d_in[5];
    const float* Wf = (const float*)d_in[6];
    const float* bf = (const float*)d_in[7];

    const int N = in_sizes[0] / 64;
    const int E = in_sizes[1] / 2;
    const int* src = ei;
    const int* dst = ei + E;

    // workspace carve-up (re-poisoned to 0xAA each call; everything is
    // fully (re)written before being read)
    char* ws = (char*)d_ws;
    size_t off = 0;
    auto alloc = [&](size_t bytes) -> void* {
        void* p = ws + off;
        off = (off + bytes + 255) & ~(size_t)255;
        return p;
    };
    int*   deg     = (int*)alloc((size_t)N * 4);
    float* dinv    = (float*)alloc((size_t)N * 4);
    int*   offs    = (int*)alloc((size_t)(N + 1) * 4);
    int*   cursor  = (int*)alloc((size_t)N * 4);
    int*   csr_src = (int*)alloc((size_t)E * 4);
    float* csr_w   = (float*)alloc((size_t)E * 4);
    float* A       = (float*)alloc((size_t)N * 64 * 4);
    float* B       = (float*)alloc((size_t)N * 64 * 4);

    // ---- CSR build (once per call, reused by both conv layers) ----
    zero_i32_kernel<<<(N + 255) / 256, 256, 0, stream>>>(deg, N);
    hist_kernel<<<2048, 256, 0, stream>>>(dst, E, deg);
    dinv_kernel<<<(N + 255) / 256, 256, 0, stream>>>(deg, dinv, N);
    scan_kernel<<<1, 1024, 0, stream>>>(deg, offs, cursor, N, E);
    scatter_kernel<<<2048, 256, 0, stream>>>(src, dst, E, dinv, cursor, csr_src, csr_w);

    // ---- layer 1: A = x@W1 ; B = relu(agg(A) + b1) ----
    gemm_kernel<64, false><<<(N + 15) / 16, 256, 0, stream>>>(x, W1, nullptr, A, N);
    agg_kernel<true><<<(N + 15) / 16, 256, 0, stream>>>(A, offs, csr_src, csr_w, dinv, b1, B, N);

    // ---- layer 2: A = B@W2 ; B = relu(agg(A) + b2) ----
    gemm_kernel<64, false><<<(N + 15) / 16, 256, 0, stream>>>(B, W2, nullptr, A, N);
    agg_kernel<true><<<(N + 15) / 16, 256, 0, stream>>>(A, offs, csr_src, csr_w, dinv, b2, B, N);

    // ---- head: out = B@Wf + bf ----
    gemm_kernel<32, true><<<(N + 31) / 32, 256, 0, stream>>>(B, Wf, bf, (float*)d_out, N);
}

// Round 2
// 543.377 us; speedup vs baseline: 1.0892x; 1.0892x over previous
//
#include <hip/hip_runtime.h>

// ---------------------------------------------------------------------------
// 2-layer GCN + linear head on MI355X.
// CSR build once per call (int atomics only), then per-layer:
//   t = h @ W  (dense, LDS-staged)
//   h' = relu(dinv_i * sum_e w_e * t[src_e] + dinv_i^2 * t[i] + b)
// R2: scatter writes ONE packed 8B (src, w) record per edge (was 2x4B to two
//     arrays -> 12x write amplification, 155MB WRITE_SIZE, 140us).
//     Scan rewritten with wave shfl (2 barriers/chunk instead of 30).
// ---------------------------------------------------------------------------

__global__ void zero_i32_kernel(int* __restrict__ p, int n) {
    int i = blockIdx.x * blockDim.x + threadIdx.x;
    if (i < n) p[i] = 0;
}

__global__ void hist_kernel(const int* __restrict__ dst, int E, int* __restrict__ deg) {
    int i = blockIdx.x * blockDim.x + threadIdx.x;
    int stride = gridDim.x * blockDim.x;
    for (; i < E; i += stride) atomicAdd(&deg[dst[i]], 1);
}

__global__ void dinv_kernel(const int* __restrict__ deg, float* __restrict__ dinv, int N) {
    int i = blockIdx.x * blockDim.x + threadIdx.x;
    if (i < N) dinv[i] = 1.0f / sqrtf((float)deg[i] + 1.0f);
}

// Single-block exclusive scan of deg -> offs (+ cursor copy).
// 1024 thr = 16 waves; wave-level shfl scan, 2-3 barriers per 4096-elem chunk.
__global__ __launch_bounds__(1024) void scan_kernel(const int* __restrict__ deg,
                                                    int* __restrict__ offs,
                                                    int* __restrict__ cursor,
                                                    int N, int E) {
    __shared__ int wsum[16];
    __shared__ int wpre[16];
    const int tid = threadIdx.x;
    const int lane = tid & 63;
    const int wave = tid >> 6;
    int carry = 0;
    const int CH = 4096;
    for (int base = 0; base < N; base += CH) {
        int v[4];
        int s = 0;
#pragma unroll
        for (int j = 0; j < 4; j++) {
            int idx = base + tid * 4 + j;
            v[j] = (idx < N) ? deg[idx] : 0;
            s += v[j];
        }
        // inclusive wave scan of s
        int inc = s;
#pragma unroll
        for (int o = 1; o < 64; o <<= 1) {
            int t = __shfl_up(inc, o, 64);
            if (lane >= o) inc += t;
        }
        if (lane == 63) wsum[wave] = inc;
        __syncthreads();
        if (wave == 0 && lane < 16) {
            int ws = wsum[lane];
            int winc = ws;
#pragma unroll
            for (int o = 1; o < 16; o <<= 1) {
                int t = __shfl_up(winc, o, 64);
                if (lane >= o) winc += t;
            }
            wpre[lane] = winc - ws;  // exclusive wave prefix
        }
        __syncthreads();
        int run = carry + wpre[wave] + (inc - s);
#pragma unroll
        for (int j = 0; j < 4; j++) {
            int idx = base + tid * 4 + j;
            if (idx < N) { offs[idx] = run; cursor[idx] = run; }
            run += v[j];
        }
        carry += wpre[15] + wsum[15];
        __syncthreads();  // protect wsum reuse next chunk
    }
    if (tid == 0) offs[N] = E;
}

// One packed 8B record per edge: {src, bitcast(dinv[src])}.
__global__ void scatter_kernel(const int* __restrict__ src, const int* __restrict__ dst,
                               int E, const float* __restrict__ dinv,
                               int* __restrict__ cursor, int2* __restrict__ csr_rec) {
    int i = blockIdx.x * blockDim.x + threadIdx.x;
    int stride = gridDim.x * blockDim.x;
    for (; i < E; i += stride) {
        int s = src[i];
        int d = dst[i];
        int pos = atomicAdd(&cursor[d], 1);
        csr_rec[pos] = make_int2(s, __float_as_int(dinv[s]));
    }
}

// Y[N,OUTC] = X[N,64] @ W[64,OUTC] (+ bias). Block 256 threads.
template <int OUTC, bool BIAS>
__global__ __launch_bounds__(256) void gemm_kernel(const float* __restrict__ X,
                                                   const float* __restrict__ W,
                                                   const float* __restrict__ bias,
                                                   float* __restrict__ Y, int N) {
    constexpr int TPR = OUTC / 4;    // threads per row
    constexpr int RPB = 256 / TPR;   // rows per block
    __shared__ float Ws[64 * OUTC];
    __shared__ float Xs[RPB * 65];   // +1 pad: bank-conflict-free column reads

    const int tid = threadIdx.x;
    const int row0 = blockIdx.x * RPB;

    for (int l = tid; l < 64 * OUTC / 4; l += 256) {
        ((float4*)Ws)[l] = ((const float4*)W)[l];
    }
    for (int l = tid; l < RPB * 16; l += 256) {
        int r = l / 16, kq = l % 16;
        float4 xv = make_float4(0.f, 0.f, 0.f, 0.f);
        if (row0 + r < N) xv = ((const float4*)(X + (long)(row0 + r) * 64))[kq];
        Xs[r * 65 + kq * 4 + 0] = xv.x;
        Xs[r * 65 + kq * 4 + 1] = xv.y;
        Xs[r * 65 + kq * 4 + 2] = xv.z;
        Xs[r * 65 + kq * 4 + 3] = xv.w;
    }
    __syncthreads();

    const int r = tid / TPR;
    const int c4 = tid % TPR;
    float4 acc = make_float4(0.f, 0.f, 0.f, 0.f);
#pragma unroll
    for (int k = 0; k < 64; k++) {
        float x = Xs[r * 65 + k];
        float4 w = *(const float4*)&Ws[k * OUTC + c4 * 4];
        acc.x += x * w.x;
        acc.y += x * w.y;
        acc.z += x * w.z;
        acc.w += x * w.w;
    }
    const int row = row0 + r;
    if (row < N) {
        if (BIAS) {
            float4 b = *(const float4*)&bias[c4 * 4];
            acc.x += b.x; acc.y += b.y; acc.z += b.z; acc.w += b.w;
        }
        *(float4*)&Y[(long)row * OUTC + c4 * 4] = acc;
    }
}

// out[i] = relu( dinv_i * sum_e w_e * T[src_e] + dinv_i^2 * T[i] + b )
// 16 lanes per node, float4 per lane (64 features). 16 nodes per 256-thr block.
template <bool RELU>
__global__ __launch_bounds__(256) void agg_kernel(const float* __restrict__ T,
                                                  const int* __restrict__ offs,
                                                  const int2* __restrict__ csr_rec,
                                                  const float* __restrict__ dinv,
                                                  const float* __restrict__ bias,
                                                  float* __restrict__ Y, int N) {
    const int tid = threadIdx.x;
    const int node = blockIdx.x * 16 + (tid >> 4);
    const int l16 = tid & 15;
    if (node >= N) return;

    const int start = offs[node];
    const int end = offs[node + 1];
    float4 acc = make_float4(0.f, 0.f, 0.f, 0.f);
    for (int e = start; e < end; e++) {
        const int2 rec = csr_rec[e];
        const int s = rec.x;
        const float w = __int_as_float(rec.y);
        const float4 hv = *(const float4*)&T[(long)s * 64 + l16 * 4];
        acc.x += w * hv.x;
        acc.y += w * hv.y;
        acc.z += w * hv.z;
        acc.w += w * hv.w;
    }
    const float di = dinv[node];
    const float dii = di * di;
    const float4 self = *(const float4*)&T[(long)node * 64 + l16 * 4];
    const float4 b4 = *(const float4*)&bias[l16 * 4];
    float4 o;
    o.x = di * acc.x + dii * self.x + b4.x;
    o.y = di * acc.y + dii * self.y + b4.y;
    o.z = di * acc.z + dii * self.z + b4.z;
    o.w = di * acc.w + dii * self.w + b4.w;
    if (RELU) {
        o.x = fmaxf(o.x, 0.f);
        o.y = fmaxf(o.y, 0.f);
        o.z = fmaxf(o.z, 0.f);
        o.w = fmaxf(o.w, 0.f);
    }
    *(float4*)&Y[(long)node * 64 + l16 * 4] = o;
}

extern "C" void kernel_launch(void* const* d_in, const int* in_sizes, int n_in,
                              void* d_out, int out_size, void* d_ws, size_t ws_size,
                              hipStream_t stream) {
    const float* x  = (const float*)d_in[0];
    const int*   ei = (const int*)d_in[1];
    const float* W1 = (const float*)d_in[2];
    const float* b1 = (const float*)d_in[3];
    const float* W2 = (const float*)d_in[4];
    const float* b2 = (const float*)d_in[5];
    const float* Wf = (const float*)d_in[6];
    const float* bf = (const float*)d_in[7];

    const int N = in_sizes[0] / 64;
    const int E = in_sizes[1] / 2;
    const int* src = ei;
    const int* dst = ei + E;

    char* ws = (char*)d_ws;
    size_t off = 0;
    auto alloc = [&](size_t bytes) -> void* {
        void* p = ws + off;
        off = (off + bytes + 255) & ~(size_t)255;
        return p;
    };
    int*   deg     = (int*)alloc((size_t)N * 4);
    float* dinv    = (float*)alloc((size_t)N * 4);
    int*   offs    = (int*)alloc((size_t)(N + 1) * 4);
    int*   cursor  = (int*)alloc((size_t)N * 4);
    int2*  csr_rec = (int2*)alloc((size_t)E * 8);
    float* A       = (float*)alloc((size_t)N * 64 * 4);
    float* B       = (float*)alloc((size_t)N * 64 * 4);

    // ---- CSR build (once per call, reused by both conv layers) ----
    zero_i32_kernel<<<(N + 255) / 256, 256, 0, stream>>>(deg, N);
    hist_kernel<<<2048, 256, 0, stream>>>(dst, E, deg);
    dinv_kernel<<<(N + 255) / 256, 256, 0, stream>>>(deg, dinv, N);
    scan_kernel<<<1, 1024, 0, stream>>>(deg, offs, cursor, N, E);
    scatter_kernel<<<2048, 256, 0, stream>>>(src, dst, E, dinv, cursor, csr_rec);

    // ---- layer 1: A = x@W1 ; B = relu(agg(A) + b1) ----
    gemm_kernel<64, false><<<(N + 15) / 16, 256, 0, stream>>>(x, W1, nullptr, A, N);
    agg_kernel<true><<<(N + 15) / 16, 256, 0, stream>>>(A, offs, csr_rec, dinv, b1, B, N);

    // ---- layer 2: A = B@W2 ; B = relu(agg(A) + b2) ----
    gemm_kernel<64, false><<<(N + 15) / 16, 256, 0, stream>>>(B, W2, nullptr, A, N);
    agg_kernel<true><<<(N + 15) / 16, 256, 0, stream>>>(A, offs, csr_rec, dinv, b2, B, N);

    // ---- head: out = B@Wf + bf ----
    gemm_kernel<32, true><<<(N + 31) / 32, 256, 0, stream>>>(B, Wf, bf, (float*)d_out, N);
}

// Round 3
// 350.604 us; speedup vs baseline: 1.6881x; 1.5498x over previous
//
#include <hip/hip_runtime.h>

// ---------------------------------------------------------------------------
// 2-layer GCN + linear head on MI355X.
// R3: CSR build via two-phase counting sort (coarse radix partition by
//     dst>>9 into 196 buckets, then per-bucket LDS count+scan+scatter).
//     Kills the random-scatter write amplification (101MB -> ~14MB) and
//     eliminates hist/scan/dinv kernels. dinv[src] folded into GEMM epilogue
//     (T' = dinv_row * X@W), so CSR record is 4B src only:
//       out_i = relu( dinv_i * (sum_e T'[src_e] + T'[i]) + b )
// ---------------------------------------------------------------------------

#define NODE_SHIFT 9
#define NODES_PER_BKT 512

__global__ void zero_i32_kernel(int* __restrict__ p, int n) {
    int i = blockIdx.x * blockDim.x + threadIdx.x;
    if (i < n) p[i] = 0;
}

// Per-block LDS histogram of dst>>NODE_SHIFT over a contiguous chunk.
__global__ __launch_bounds__(256) void coarse_hist_kernel(const int* __restrict__ dst, int E,
                                                          int* __restrict__ bkt_cnt,
                                                          int K1, int CHK) {
    __shared__ int lcnt[256];
    const int tid = threadIdx.x;
    const int start = blockIdx.x * CHK;
    const int end = min(E, start + CHK);
    for (int k = tid; k < K1; k += 256) lcnt[k] = 0;
    __syncthreads();
    for (int i = start + tid; i < end; i += 256)
        atomicAdd(&lcnt[dst[i] >> NODE_SHIFT], 1);
    __syncthreads();
    for (int k = tid; k < K1; k += 256)
        if (lcnt[k]) atomicAdd(&bkt_cnt[k], lcnt[k]);
}

// Exclusive scan of K1 (<=256) bucket counts. One wave, 4 entries/lane.
__global__ __launch_bounds__(64) void bucket_scan_kernel(const int* __restrict__ bkt_cnt,
                                                         int* __restrict__ bkt_start,
                                                         int* __restrict__ bkt_cursor,
                                                         int K1, int E) {
    const int lane = threadIdx.x;
    int v[4];
    int s = 0;
#pragma unroll
    for (int j = 0; j < 4; j++) {
        int idx = lane * 4 + j;
        v[j] = (idx < K1) ? bkt_cnt[idx] : 0;
        s += v[j];
    }
    int inc = s;
#pragma unroll
    for (int o = 1; o < 64; o <<= 1) {
        int t = __shfl_up(inc, o, 64);
        if (lane >= o) inc += t;
    }
    int run = inc - s;  // exclusive
#pragma unroll
    for (int j = 0; j < 4; j++) {
        int idx = lane * 4 + j;
        if (idx < K1) { bkt_start[idx] = run; bkt_cursor[idx] = run; }
        run += v[j];
    }
    if (lane == 0) bkt_start[K1] = E;
}

// Partition edges into coarse buckets: LDS hist -> range reservation -> write.
// staging[pos] = (dst, src). Writes are ~contiguous runs per bucket.
__global__ __launch_bounds__(256) void partition_kernel(const int* __restrict__ src,
                                                        const int* __restrict__ dst, int E,
                                                        int* __restrict__ bkt_cursor,
                                                        int2* __restrict__ staging,
                                                        int K1, int CHK) {
    __shared__ int lcnt[256];
    __shared__ int lcur[256];
    const int tid = threadIdx.x;
    const int start = blockIdx.x * CHK;
    const int end = min(E, start + CHK);
    for (int k = tid; k < K1; k += 256) lcnt[k] = 0;
    __syncthreads();
    for (int i = start + tid; i < end; i += 256)
        atomicAdd(&lcnt[dst[i] >> NODE_SHIFT], 1);
    __syncthreads();
    for (int k = tid; k < K1; k += 256) {
        int c = lcnt[k];
        lcur[k] = c ? atomicAdd(&bkt_cursor[k], c) : 0;
    }
    __syncthreads();
    for (int i = start + tid; i < end; i += 256) {
        int d = dst[i];
        int s = src[i];
        int pos = atomicAdd(&lcur[d >> NODE_SHIFT], 1);
        staging[pos] = make_int2(d, s);
    }
}

// One block per bucket: LDS degree count -> scan -> offs/dinv -> final CSR.
__global__ __launch_bounds__(256) void bucket_build_kernel(const int2* __restrict__ staging,
                                                           const int* __restrict__ bkt_start,
                                                           float* __restrict__ dinv,
                                                           int* __restrict__ offs,
                                                           int* __restrict__ csr_src,
                                                           int N, int E) {
    __shared__ int cnt[NODES_PER_BKT];
    __shared__ int wsum[4];
    const int tid = threadIdx.x;
    const int node0 = blockIdx.x * NODES_PER_BKT;
    const int estart = bkt_start[blockIdx.x];
    const int eend = bkt_start[blockIdx.x + 1];

    cnt[tid] = 0;
    cnt[tid + 256] = 0;
    __syncthreads();
    for (int e = estart + tid; e < eend; e += 256)
        atomicAdd(&cnt[staging[e].x - node0], 1);
    __syncthreads();

    // exclusive scan over 512 counts (2 per thread), wave shfl + combine
    const int lane = tid & 63;
    const int wave = tid >> 6;
    int c0 = cnt[2 * tid];
    int c1 = cnt[2 * tid + 1];
    int s = c0 + c1;
    int inc = s;
#pragma unroll
    for (int o = 1; o < 64; o <<= 1) {
        int t = __shfl_up(inc, o, 64);
        if (lane >= o) inc += t;
    }
    if (lane == 63) wsum[wave] = inc;
    __syncthreads();
    int wpre = 0;
#pragma unroll
    for (int w = 0; w < 4; w++) wpre += (w < wave) ? wsum[w] : 0;
    const int excl = wpre + inc - s;  // edges before node 2*tid within bucket

    const int n0 = node0 + 2 * tid;
    const int n1 = n0 + 1;
    const int p0 = estart + excl;
    const int p1 = p0 + c0;
    __syncthreads();  // cnt reuse as cursor
    if (n0 < N) {
        offs[n0] = p0;
        dinv[n0] = rsqrtf((float)c0 + 1.0f);
        cnt[2 * tid] = p0;
    }
    if (n1 < N) {
        offs[n1] = p1;
        dinv[n1] = rsqrtf((float)c1 + 1.0f);
        cnt[2 * tid + 1] = p1;
    }
    __syncthreads();
    for (int e = estart + tid; e < eend; e += 256) {
        int2 r = staging[e];
        int pos = atomicAdd(&cnt[r.x - node0], 1);
        csr_src[pos] = r.y;
    }
    if (blockIdx.x == 0 && tid == 0) offs[N] = E;
}

// Y[N,OUTC] = (X[N,64] @ W[64,OUTC]) * (SCALE ? dinv[row] : 1) (+ bias)
template <int OUTC, bool BIAS, bool SCALE>
__global__ __launch_bounds__(256) void gemm_kernel(const float* __restrict__ X,
                                                   const float* __restrict__ W,
                                                   const float* __restrict__ bias,
                                                   const float* __restrict__ dinv,
                                                   float* __restrict__ Y, int N) {
    constexpr int TPR = OUTC / 4;    // threads per row
    constexpr int RPB = 256 / TPR;   // rows per block
    __shared__ float Ws[64 * OUTC];
    __shared__ float Xs[RPB * 65];

    const int tid = threadIdx.x;
    const int row0 = blockIdx.x * RPB;

    for (int l = tid; l < 64 * OUTC / 4; l += 256) {
        ((float4*)Ws)[l] = ((const float4*)W)[l];
    }
    for (int l = tid; l < RPB * 16; l += 256) {
        int r = l / 16, kq = l % 16;
        float4 xv = make_float4(0.f, 0.f, 0.f, 0.f);
        if (row0 + r < N) xv = ((const float4*)(X + (long)(row0 + r) * 64))[kq];
        Xs[r * 65 + kq * 4 + 0] = xv.x;
        Xs[r * 65 + kq * 4 + 1] = xv.y;
        Xs[r * 65 + kq * 4 + 2] = xv.z;
        Xs[r * 65 + kq * 4 + 3] = xv.w;
    }
    __syncthreads();

    const int r = tid / TPR;
    const int c4 = tid % TPR;
    float4 acc = make_float4(0.f, 0.f, 0.f, 0.f);
#pragma unroll
    for (int k = 0; k < 64; k++) {
        float x = Xs[r * 65 + k];
        float4 w = *(const float4*)&Ws[k * OUTC + c4 * 4];
        acc.x += x * w.x;
        acc.y += x * w.y;
        acc.z += x * w.z;
        acc.w += x * w.w;
    }
    const int row = row0 + r;
    if (row < N) {
        if (SCALE) {
            float d = dinv[row];
            acc.x *= d; acc.y *= d; acc.z *= d; acc.w *= d;
        }
        if (BIAS) {
            float4 b = *(const float4*)&bias[c4 * 4];
            acc.x += b.x; acc.y += b.y; acc.z += b.z; acc.w += b.w;
        }
        *(float4*)&Y[(long)row * OUTC + c4 * 4] = acc;
    }
}

// out[i] = relu( dinv_i * (sum_e T'[src_e] + T'[i]) + b ),  T' pre-scaled by dinv_row.
// 16 lanes per node, float4 per lane (64 features).
template <bool RELU>
__global__ __launch_bounds__(256) void agg_kernel(const float* __restrict__ T,
                                                  const int* __restrict__ offs,
                                                  const int* __restrict__ csr_src,
                                                  const float* __restrict__ dinv,
                                                  const float* __restrict__ bias,
                                                  float* __restrict__ Y, int N) {
    const int tid = threadIdx.x;
    const int node = blockIdx.x * 16 + (tid >> 4);
    const int l16 = tid & 15;
    if (node >= N) return;

    const int start = offs[node];
    const int end = offs[node + 1];
    float4 acc = make_float4(0.f, 0.f, 0.f, 0.f);
    for (int e = start; e < end; e++) {
        const int s = csr_src[e];
        const float4 hv = *(const float4*)&T[(long)s * 64 + l16 * 4];
        acc.x += hv.x;
        acc.y += hv.y;
        acc.z += hv.z;
        acc.w += hv.w;
    }
    const float di = dinv[node];
    const float4 self = *(const float4*)&T[(long)node * 64 + l16 * 4];
    const float4 b4 = *(const float4*)&bias[l16 * 4];
    float4 o;
    o.x = di * (acc.x + self.x) + b4.x;
    o.y = di * (acc.y + self.y) + b4.y;
    o.z = di * (acc.z + self.z) + b4.z;
    o.w = di * (acc.w + self.w) + b4.w;
    if (RELU) {
        o.x = fmaxf(o.x, 0.f);
        o.y = fmaxf(o.y, 0.f);
        o.z = fmaxf(o.z, 0.f);
        o.w = fmaxf(o.w, 0.f);
    }
    *(float4*)&Y[(long)node * 64 + l16 * 4] = o;
}

extern "C" void kernel_launch(void* const* d_in, const int* in_sizes, int n_in,
                              void* d_out, int out_size, void* d_ws, size_t ws_size,
                              hipStream_t stream) {
    const float* x  = (const float*)d_in[0];
    const int*   ei = (const int*)d_in[1];
    const float* W1 = (const float*)d_in[2];
    const float* b1 = (const float*)d_in[3];
    const float* W2 = (const float*)d_in[4];
    const float* b2 = (const float*)d_in[5];
    const float* Wf = (const float*)d_in[6];
    const float* bf = (const float*)d_in[7];

    const int N = in_sizes[0] / 64;
    const int E = in_sizes[1] / 2;
    const int* src = ei;
    const int* dst = ei + E;
    const int K1 = (N + NODES_PER_BKT - 1) / NODES_PER_BKT;  // 196 for N=100k

    char* ws = (char*)d_ws;
    size_t off = 0;
    auto alloc = [&](size_t bytes) -> void* {
        void* p = ws + off;
        off = (off + bytes + 255) & ~(size_t)255;
        return p;
    };
    int*   bkt_cnt    = (int*)alloc(256 * 4);
    int*   bkt_start  = (int*)alloc(257 * 4);
    int*   bkt_cursor = (int*)alloc(256 * 4);
    float* dinv       = (float*)alloc((size_t)N * 4);
    int*   offs       = (int*)alloc((size_t)(N + 1) * 4);
    int*   csr_src    = (int*)alloc((size_t)E * 4);
    float* A          = (float*)alloc((size_t)N * 64 * 4);   // aliases staging
    float* B          = (float*)alloc((size_t)N * 64 * 4);
    int2*  staging    = (int2*)A;  // E*8 = 12.8MB <= N*256 = 25.6MB; dead before gemm1

    const int NB = 128;                 // partition blocks
    const int CHK = (E + NB - 1) / NB;  // edges per block chunk

    // ---- CSR build: counting sort, no random scatter ----
    zero_i32_kernel<<<1, 256, 0, stream>>>(bkt_cnt, K1);
    coarse_hist_kernel<<<NB, 256, 0, stream>>>(dst, E, bkt_cnt, K1, CHK);
    bucket_scan_kernel<<<1, 64, 0, stream>>>(bkt_cnt, bkt_start, bkt_cursor, K1, E);
    partition_kernel<<<NB, 256, 0, stream>>>(src, dst, E, bkt_cursor, staging, K1, CHK);
    bucket_build_kernel<<<K1, 256, 0, stream>>>(staging, bkt_start, dinv, offs, csr_src, N, E);

    // ---- layer 1: A = dinv*(x@W1) ; B = relu(dinv_i*(agg+self) + b1) ----
    gemm_kernel<64, false, true><<<(N + 15) / 16, 256, 0, stream>>>(x, W1, nullptr, dinv, A, N);
    agg_kernel<true><<<(N + 15) / 16, 256, 0, stream>>>(A, offs, csr_src, dinv, b1, B, N);

    // ---- layer 2 ----
    gemm_kernel<64, false, true><<<(N + 15) / 16, 256, 0, stream>>>(B, W2, nullptr, dinv, A, N);
    agg_kernel<true><<<(N + 15) / 16, 256, 0, stream>>>(A, offs, csr_src, dinv, b2, B, N);

    // ---- head: out = B@Wf + bf ----
    gemm_kernel<32, true, false><<<(N + 31) / 32, 256, 0, stream>>>(B, Wf, bf, nullptr, (float*)d_out, N);
}

// Round 4
// 326.747 us; speedup vs baseline: 1.8114x; 1.0730x over previous
//
#include <hip/hip_runtime.h>

// ---------------------------------------------------------------------------
// 2-layer GCN + linear head on MI355X.
// R3: counting-sort CSR build (coarse radix by dst>>9, per-bucket LDS build).
// R4: agg_kernel software-pipelined — 8 independent gathers in flight per
//     wave (was 1: serial idx->gather dependent chain, latency-bound at
//     39% HBM / 11% VALU). Next-batch indices load before the accumulate's
//     waitcnt, so index latency also overlaps gather latency.
// ---------------------------------------------------------------------------

#define NODE_SHIFT 9
#define NODES_PER_BKT 512

__global__ void zero_i32_kernel(int* __restrict__ p, int n) {
    int i = blockIdx.x * blockDim.x + threadIdx.x;
    if (i < n) p[i] = 0;
}

// Per-block LDS histogram of dst>>NODE_SHIFT over a contiguous chunk.
__global__ __launch_bounds__(256) void coarse_hist_kernel(const int* __restrict__ dst, int E,
                                                          int* __restrict__ bkt_cnt,
                                                          int K1, int CHK) {
    __shared__ int lcnt[256];
    const int tid = threadIdx.x;
    const int start = blockIdx.x * CHK;
    const int end = min(E, start + CHK);
    for (int k = tid; k < K1; k += 256) lcnt[k] = 0;
    __syncthreads();
    for (int i = start + tid; i < end; i += 256)
        atomicAdd(&lcnt[dst[i] >> NODE_SHIFT], 1);
    __syncthreads();
    for (int k = tid; k < K1; k += 256)
        if (lcnt[k]) atomicAdd(&bkt_cnt[k], lcnt[k]);
}

// Exclusive scan of K1 (<=256) bucket counts. One wave, 4 entries/lane.
__global__ __launch_bounds__(64) void bucket_scan_kernel(const int* __restrict__ bkt_cnt,
                                                         int* __restrict__ bkt_start,
                                                         int* __restrict__ bkt_cursor,
                                                         int K1, int E) {
    const int lane = threadIdx.x;
    int v[4];
    int s = 0;
#pragma unroll
    for (int j = 0; j < 4; j++) {
        int idx = lane * 4 + j;
        v[j] = (idx < K1) ? bkt_cnt[idx] : 0;
        s += v[j];
    }
    int inc = s;
#pragma unroll
    for (int o = 1; o < 64; o <<= 1) {
        int t = __shfl_up(inc, o, 64);
        if (lane >= o) inc += t;
    }
    int run = inc - s;  // exclusive
#pragma unroll
    for (int j = 0; j < 4; j++) {
        int idx = lane * 4 + j;
        if (idx < K1) { bkt_start[idx] = run; bkt_cursor[idx] = run; }
        run += v[j];
    }
    if (lane == 0) bkt_start[K1] = E;
}

// Partition edges into coarse buckets: LDS hist -> range reservation -> write.
__global__ __launch_bounds__(256) void partition_kernel(const int* __restrict__ src,
                                                        const int* __restrict__ dst, int E,
                                                        int* __restrict__ bkt_cursor,
                                                        int2* __restrict__ staging,
                                                        int K1, int CHK) {
    __shared__ int lcnt[256];
    __shared__ int lcur[256];
    const int tid = threadIdx.x;
    const int start = blockIdx.x * CHK;
    const int end = min(E, start + CHK);
    for (int k = tid; k < K1; k += 256) lcnt[k] = 0;
    __syncthreads();
    for (int i = start + tid; i < end; i += 256)
        atomicAdd(&lcnt[dst[i] >> NODE_SHIFT], 1);
    __syncthreads();
    for (int k = tid; k < K1; k += 256) {
        int c = lcnt[k];
        lcur[k] = c ? atomicAdd(&bkt_cursor[k], c) : 0;
    }
    __syncthreads();
    for (int i = start + tid; i < end; i += 256) {
        int d = dst[i];
        int s = src[i];
        int pos = atomicAdd(&lcur[d >> NODE_SHIFT], 1);
        staging[pos] = make_int2(d, s);
    }
}

// One block per bucket: LDS degree count -> scan -> offs/dinv -> final CSR.
__global__ __launch_bounds__(256) void bucket_build_kernel(const int2* __restrict__ staging,
                                                           const int* __restrict__ bkt_start,
                                                           float* __restrict__ dinv,
                                                           int* __restrict__ offs,
                                                           int* __restrict__ csr_src,
                                                           int N, int E) {
    __shared__ int cnt[NODES_PER_BKT];
    __shared__ int wsum[4];
    const int tid = threadIdx.x;
    const int node0 = blockIdx.x * NODES_PER_BKT;
    const int estart = bkt_start[blockIdx.x];
    const int eend = bkt_start[blockIdx.x + 1];

    cnt[tid] = 0;
    cnt[tid + 256] = 0;
    __syncthreads();
    for (int e = estart + tid; e < eend; e += 256)
        atomicAdd(&cnt[staging[e].x - node0], 1);
    __syncthreads();

    const int lane = tid & 63;
    const int wave = tid >> 6;
    int c0 = cnt[2 * tid];
    int c1 = cnt[2 * tid + 1];
    int s = c0 + c1;
    int inc = s;
#pragma unroll
    for (int o = 1; o < 64; o <<= 1) {
        int t = __shfl_up(inc, o, 64);
        if (lane >= o) inc += t;
    }
    if (lane == 63) wsum[wave] = inc;
    __syncthreads();
    int wpre = 0;
#pragma unroll
    for (int w = 0; w < 4; w++) wpre += (w < wave) ? wsum[w] : 0;
    const int excl = wpre + inc - s;

    const int n0 = node0 + 2 * tid;
    const int n1 = n0 + 1;
    const int p0 = estart + excl;
    const int p1 = p0 + c0;
    __syncthreads();  // cnt reuse as cursor
    if (n0 < N) {
        offs[n0] = p0;
        dinv[n0] = rsqrtf((float)c0 + 1.0f);
        cnt[2 * tid] = p0;
    }
    if (n1 < N) {
        offs[n1] = p1;
        dinv[n1] = rsqrtf((float)c1 + 1.0f);
        cnt[2 * tid + 1] = p1;
    }
    __syncthreads();
    for (int e = estart + tid; e < eend; e += 256) {
        int2 r = staging[e];
        int pos = atomicAdd(&cnt[r.x - node0], 1);
        csr_src[pos] = r.y;
    }
    if (blockIdx.x == 0 && tid == 0) offs[N] = E;
}

// Y[N,OUTC] = (X[N,64] @ W[64,OUTC]) * (SCALE ? dinv[row] : 1) (+ bias)
template <int OUTC, bool BIAS, bool SCALE>
__global__ __launch_bounds__(256) void gemm_kernel(const float* __restrict__ X,
                                                   const float* __restrict__ W,
                                                   const float* __restrict__ bias,
                                                   const float* __restrict__ dinv,
                                                   float* __restrict__ Y, int N) {
    constexpr int TPR = OUTC / 4;
    constexpr int RPB = 256 / TPR;
    __shared__ float Ws[64 * OUTC];
    __shared__ float Xs[RPB * 65];

    const int tid = threadIdx.x;
    const int row0 = blockIdx.x * RPB;

    for (int l = tid; l < 64 * OUTC / 4; l += 256) {
        ((float4*)Ws)[l] = ((const float4*)W)[l];
    }
    for (int l = tid; l < RPB * 16; l += 256) {
        int r = l / 16, kq = l % 16;
        float4 xv = make_float4(0.f, 0.f, 0.f, 0.f);
        if (row0 + r < N) xv = ((const float4*)(X + (long)(row0 + r) * 64))[kq];
        Xs[r * 65 + kq * 4 + 0] = xv.x;
        Xs[r * 65 + kq * 4 + 1] = xv.y;
        Xs[r * 65 + kq * 4 + 2] = xv.z;
        Xs[r * 65 + kq * 4 + 3] = xv.w;
    }
    __syncthreads();

    const int r = tid / TPR;
    const int c4 = tid % TPR;
    float4 acc = make_float4(0.f, 0.f, 0.f, 0.f);
#pragma unroll
    for (int k = 0; k < 64; k++) {
        float x = Xs[r * 65 + k];
        float4 w = *(const float4*)&Ws[k * OUTC + c4 * 4];
        acc.x += x * w.x;
        acc.y += x * w.y;
        acc.z += x * w.z;
        acc.w += x * w.w;
    }
    const int row = row0 + r;
    if (row < N) {
        if (SCALE) {
            float d = dinv[row];
            acc.x *= d; acc.y *= d; acc.z *= d; acc.w *= d;
        }
        if (BIAS) {
            float4 b = *(const float4*)&bias[c4 * 4];
            acc.x += b.x; acc.y += b.y; acc.z += b.z; acc.w += b.w;
        }
        *(float4*)&Y[(long)row * OUTC + c4 * 4] = acc;
    }
}

// out[i] = relu( dinv_i * (sum_e T'[src_e] + T'[i]) + b ),  T' pre-scaled by dinv_row.
// 16 lanes/node, float4/lane. R4: 8 gathers in flight, pipelined index loads.
template <bool RELU>
__global__ __launch_bounds__(256) void agg_kernel(const float* __restrict__ T,
                                                  const int* __restrict__ offs,
                                                  const int* __restrict__ csr_src,
                                                  const float* __restrict__ dinv,
                                                  const float* __restrict__ bias,
                                                  float* __restrict__ Y, int N) {
    const int tid = threadIdx.x;
    const int node = blockIdx.x * 16 + (tid >> 4);
    const int l16 = tid & 15;
    if (node >= N) return;

    const int start = offs[node];
    const int n_edges = offs[node + 1] - start;
    const int* ep = csr_src + start;
    const int fo = l16 * 4;  // feature offset within row

    float4 acc = make_float4(0.f, 0.f, 0.f, 0.f);

    int s[8];
    int e = 0;
    if (n_edges >= 8) {
#pragma unroll
        for (int j = 0; j < 8; j++) s[j] = ep[j];
        while (true) {
            float4 h[8];
#pragma unroll
            for (int j = 0; j < 8; j++)
                h[j] = *(const float4*)&T[(long)s[j] * 64 + fo];
            const int next = e + 8;
            const bool more = (next + 8 <= n_edges);
            if (more) {
#pragma unroll
                for (int j = 0; j < 8; j++) s[j] = ep[next + j];
            }
#pragma unroll
            for (int j = 0; j < 8; j++) {
                acc.x += h[j].x;
                acc.y += h[j].y;
                acc.z += h[j].z;
                acc.w += h[j].w;
            }
            e = next;
            if (!more) break;
        }
    }
    if (e + 4 <= n_edges) {
        int s4[4];
#pragma unroll
        for (int j = 0; j < 4; j++) s4[j] = ep[e + j];
        float4 h[4];
#pragma unroll
        for (int j = 0; j < 4; j++)
            h[j] = *(const float4*)&T[(long)s4[j] * 64 + fo];
#pragma unroll
        for (int j = 0; j < 4; j++) {
            acc.x += h[j].x;
            acc.y += h[j].y;
            acc.z += h[j].z;
            acc.w += h[j].w;
        }
        e += 4;
    }
    for (; e < n_edges; e++) {
        const float4 hv = *(const float4*)&T[(long)ep[e] * 64 + fo];
        acc.x += hv.x;
        acc.y += hv.y;
        acc.z += hv.z;
        acc.w += hv.w;
    }

    const float di = dinv[node];
    const float4 self = *(const float4*)&T[(long)node * 64 + fo];
    const float4 b4 = *(const float4*)&bias[fo];
    float4 o;
    o.x = di * (acc.x + self.x) + b4.x;
    o.y = di * (acc.y + self.y) + b4.y;
    o.z = di * (acc.z + self.z) + b4.z;
    o.w = di * (acc.w + self.w) + b4.w;
    if (RELU) {
        o.x = fmaxf(o.x, 0.f);
        o.y = fmaxf(o.y, 0.f);
        o.z = fmaxf(o.z, 0.f);
        o.w = fmaxf(o.w, 0.f);
    }
    *(float4*)&Y[(long)node * 64 + fo] = o;
}

extern "C" void kernel_launch(void* const* d_in, const int* in_sizes, int n_in,
                              void* d_out, int out_size, void* d_ws, size_t ws_size,
                              hipStream_t stream) {
    const float* x  = (const float*)d_in[0];
    const int*   ei = (const int*)d_in[1];
    const float* W1 = (const float*)d_in[2];
    const float* b1 = (const float*)d_in[3];
    const float* W2 = (const float*)d_in[4];
    const float* b2 = (const float*)d_in[5];
    const float* Wf = (const float*)d_in[6];
    const float* bf = (const float*)d_in[7];

    const int N = in_sizes[0] / 64;
    const int E = in_sizes[1] / 2;
    const int* src = ei;
    const int* dst = ei + E;
    const int K1 = (N + NODES_PER_BKT - 1) / NODES_PER_BKT;

    char* ws = (char*)d_ws;
    size_t off = 0;
    auto alloc = [&](size_t bytes) -> void* {
        void* p = ws + off;
        off = (off + bytes + 255) & ~(size_t)255;
        return p;
    };
    int*   bkt_cnt    = (int*)alloc(256 * 4);
    int*   bkt_start  = (int*)alloc(257 * 4);
    int*   bkt_cursor = (int*)alloc(256 * 4);
    float* dinv       = (float*)alloc((size_t)N * 4);
    int*   offs       = (int*)alloc((size_t)(N + 1) * 4);
    int*   csr_src    = (int*)alloc((size_t)E * 4);
    float* A          = (float*)alloc((size_t)N * 64 * 4);
    float* B          = (float*)alloc((size_t)N * 64 * 4);
    int2*  staging    = (int2*)A;  // dead before gemm1 writes A

    const int NB = 128;
    const int CHK = (E + NB - 1) / NB;

    // ---- CSR build: counting sort, no random scatter ----
    zero_i32_kernel<<<1, 256, 0, stream>>>(bkt_cnt, K1);
    coarse_hist_kernel<<<NB, 256, 0, stream>>>(dst, E, bkt_cnt, K1, CHK);
    bucket_scan_kernel<<<1, 64, 0, stream>>>(bkt_cnt, bkt_start, bkt_cursor, K1, E);
    partition_kernel<<<NB, 256, 0, stream>>>(src, dst, E, bkt_cursor, staging, K1, CHK);
    bucket_build_kernel<<<K1, 256, 0, stream>>>(staging, bkt_start, dinv, offs, csr_src, N, E);

    // ---- layer 1 ----
    gemm_kernel<64, false, true><<<(N + 15) / 16, 256, 0, stream>>>(x, W1, nullptr, dinv, A, N);
    agg_kernel<true><<<(N + 15) / 16, 256, 0, stream>>>(A, offs, csr_src, dinv, b1, B, N);

    // ---- layer 2 ----
    gemm_kernel<64, false, true><<<(N + 15) / 16, 256, 0, stream>>>(B, W2, nullptr, dinv, A, N);
    agg_kernel<true><<<(N + 15) / 16, 256, 0, stream>>>(A, offs, csr_src, dinv, b2, B, N);

    // ---- head ----
    gemm_kernel<32, true, false><<<(N + 31) / 32, 256, 0, stream>>>(B, Wf, bf, nullptr, (float*)d_out, N);
}